// Round 10
// baseline (724.876 us; speedup 1.0000x reference)
//
#include <hip/hip_runtime.h>
#include <cmath>

#define NT1  131072     // B*N total nodes at stage 1
#define ETOT 2097152    // total edges (B*N*DEG)
#define NB   64         // graphs
#define F    128        // feature dim
#define CPAD 32         // per-graph atomic counter stride (ints) = 128B line
#define MAXBLK 32       // max select-blocks per graph (stage 1: 2048/64)

// ------------------------------------------------------------------
// CSR build (on ORIGINAL node ids; reused by all 3 stages via m[])
// ------------------------------------------------------------------
__global__ void hist_kernel(const int* __restrict__ dst, int* __restrict__ deg) {
  int e = blockIdx.x * blockDim.x + threadIdx.x;
  if (e < ETOT) atomicAdd(&deg[dst[e]], 1);
}

__global__ void scan1_kernel(const int* __restrict__ deg, int* __restrict__ rowstart,
                             int* __restrict__ bsum) {
  __shared__ int ls[256];
  int base = blockIdx.x * 1024;
  int t = threadIdx.x;
  int i = base + t * 4;
  int a0 = deg[i], a1 = deg[i + 1], a2 = deg[i + 2], a3 = deg[i + 3];
  int s = a0 + a1 + a2 + a3;
  ls[t] = s;
  __syncthreads();
  for (int off = 1; off < 256; off <<= 1) {
    int v = (t >= off) ? ls[t - off] : 0;
    __syncthreads();
    ls[t] += v;
    __syncthreads();
  }
  int excl = ls[t] - s;
  rowstart[i]     = excl;
  rowstart[i + 1] = excl + a0;
  rowstart[i + 2] = excl + a0 + a1;
  rowstart[i + 3] = excl + a0 + a1 + a2;
  if (t == 255) bsum[blockIdx.x] = ls[255];
}

__global__ void scan2_kernel(int* __restrict__ bsum) {
  __shared__ int ls[128];
  int t = threadIdx.x;
  int v0 = bsum[t];
  ls[t] = v0;
  __syncthreads();
  for (int off = 1; off < 128; off <<= 1) {
    int v = (t >= off) ? ls[t - off] : 0;
    __syncthreads();
    ls[t] += v;
    __syncthreads();
  }
  bsum[t] = ls[t] - v0;   // exclusive
}

// adds block offsets; also writes cursor = rowstart (fill's atomic cursor)
__global__ void scan3_kernel(int* __restrict__ rowstart, const int* __restrict__ bsum,
                             int* __restrict__ cursor) {
  int base = blockIdx.x * 1024;
  int off = bsum[blockIdx.x];
  int i = base + threadIdx.x * 4;
  int r0 = rowstart[i] + off, r1 = rowstart[i + 1] + off;
  int r2 = rowstart[i + 2] + off, r3 = rowstart[i + 3] + off;
  rowstart[i] = r0; rowstart[i + 1] = r1; rowstart[i + 2] = r2; rowstart[i + 3] = r3;
  cursor[i] = r0; cursor[i + 1] = r1; cursor[i + 2] = r2; cursor[i + 3] = r3;
}

__global__ void fill_kernel(const int* __restrict__ src, const int* __restrict__ dst,
                            int* __restrict__ cursor, int* __restrict__ csr) {
  int e = blockIdx.x * blockDim.x + threadIdx.x;
  if (e < ETOT) {
    int pos = atomicAdd(&cursor[dst[e]], 1);
    csr[pos] = src[e];
  }
}

// identity alive-map, orig list, and stage-1 (rowstart,deg) pairs
__global__ void init_id_kernel(int* __restrict__ m, int* __restrict__ orig,
                               const int* __restrict__ rowstart,
                               const int* __restrict__ deg, int2* __restrict__ sd2) {
  int v = blockIdx.x * blockDim.x + threadIdx.x;
  m[v] = v; orig[v] = v;
  sd2[v] = make_int2(rowstart[v], deg[v]);
}

// ------------------------------------------------------------------
// Neighbor MEAN aggregation: 32-lane group per node, lane = float4
// slice, shfl-broadcast ids, 8-deep-unrolled predicated gather.
// MAP=1 folds the alive-map lookup into the id fetch (stages 2/3).
// Block 0 computes invn = 1/||pw||.
// ------------------------------------------------------------------
template <int MAP>
__global__ __launch_bounds__(256) void agg_kernel(
    const float* __restrict__ xin, const int* __restrict__ ids,
    const int* __restrict__ m, const int2* __restrict__ sd2,
    float* __restrict__ agg, const float* __restrict__ pw,
    float* __restrict__ invn) {
  if (blockIdx.x == 0 && threadIdx.x < 64) {
    int l = threadIdx.x;
    float vv = pw[l] * pw[l] + pw[l + 64] * pw[l + 64];
    #pragma unroll
    for (int o = 32; o; o >>= 1) vv += __shfl_xor(vv, o);
    if (l == 0) *invn = 1.0f / sqrtf(vv);
  }
  int swz = gridDim.x >> 3;                    // blocks per XCD slice
  int nb  = (blockIdx.x & 7) * swz + (blockIdx.x >> 3);
  int g = threadIdx.x >> 5, l = threadIdx.x & 31;
  int jd = nb * 8 + g;
  int2 sdv = sd2[jd];
  int s = sdv.x, d = sdv.y;
  float4 acc = make_float4(0.f, 0.f, 0.f, 0.f);
  int c = 0;
  for (int base = 0; base < d; base += 32) {
    int dc = min(32, d - base);
    int nbid = -1;
    if (l < dc) {
      int e = __builtin_nontemporal_load(&ids[s + base + l]);
      nbid = MAP ? m[e] : e;
    }
    int j = 0;
    for (; j + 8 <= dc; j += 8) {
      int n[8];
      float4 v[8];
      #pragma unroll
      for (int q = 0; q < 8; ++q) n[q] = __shfl(nbid, j + q, 32);
      #pragma unroll
      for (int q = 0; q < 8; ++q)
        v[q] = *(const float4*)(xin + (size_t)max(n[q], 0) * F + l * 4);
      #pragma unroll
      for (int q = 0; q < 8; ++q)
        if (n[q] >= 0) { acc.x += v[q].x; acc.y += v[q].y; acc.z += v[q].z; acc.w += v[q].w; ++c; }
    }
    for (; j + 4 <= dc; j += 4) {
      int n0 = __shfl(nbid, j, 32);
      int n1 = __shfl(nbid, j + 1, 32);
      int n2 = __shfl(nbid, j + 2, 32);
      int n3 = __shfl(nbid, j + 3, 32);
      float4 v0 = *(const float4*)(xin + (size_t)max(n0, 0) * F + l * 4);
      float4 v1 = *(const float4*)(xin + (size_t)max(n1, 0) * F + l * 4);
      float4 v2 = *(const float4*)(xin + (size_t)max(n2, 0) * F + l * 4);
      float4 v3 = *(const float4*)(xin + (size_t)max(n3, 0) * F + l * 4);
      if (n0 >= 0) { acc.x += v0.x; acc.y += v0.y; acc.z += v0.z; acc.w += v0.w; ++c; }
      if (n1 >= 0) { acc.x += v1.x; acc.y += v1.y; acc.z += v1.z; acc.w += v1.w; ++c; }
      if (n2 >= 0) { acc.x += v2.x; acc.y += v2.y; acc.z += v2.z; acc.w += v2.w; ++c; }
      if (n3 >= 0) { acc.x += v3.x; acc.y += v3.y; acc.z += v3.z; acc.w += v3.w; ++c; }
    }
    for (; j < dc; ++j) {
      int n0 = __shfl(nbid, j, 32);
      if (n0 >= 0) {
        float4 v0 = *(const float4*)(xin + (size_t)n0 * F + l * 4);
        acc.x += v0.x; acc.y += v0.y; acc.z += v0.z; acc.w += v0.w; ++c;
      }
    }
  }
  float inv = 1.0f / (float)max(c, 1);
  acc.x *= inv; acc.y *= inv; acc.z *= inv; acc.w *= inv;
  *(float4*)(agg + (size_t)jd * F + l * 4) = acc;
}

// ------------------------------------------------------------------
// Fused SAGE linear + pool scoring, BM x 128 tile / 256 threads.
// BK=32 K-tiles (8 tiles, 16 barriers/block — half of BK=16) with the
// R5 load shape: loads at loop top, short live range across one
// barrier (R6 dbuf and R8 post-barrier prefetch both regressed).
//   iter kt: load regs(kt) -> bar(prev compute done) -> write LDS ->
//            bar -> compute 32 k
//   h = relu( mean @ Wl + x @ Wr + b );  score = tanh((h.pw)*invn)
// h aliases agg — safe: block touches only its own BM rows.
// ------------------------------------------------------------------
template <int BM>
__global__ __launch_bounds__(256) void sage_gemm(
    const float* agg, const float* __restrict__ x,
    const float* __restrict__ Wl, const float* __restrict__ Wr,
    const float* __restrict__ bias, float* h,
    const float* __restrict__ pw, const float* __restrict__ invn,
    float* __restrict__ score) {
  constexpr int RQ = BM / 64;               // row quadrants (2 or 1)
  constexpr int AKV = (BM == 128) ? 4 : 2;  // A float4s staged per thread
  __shared__ float At[32][BM + 4];
  __shared__ float Wt[32][132];
  int t  = threadIdx.x;
  int tx = t & 15, ty = t >> 4;             // 16x16 thread grid
  int i0 = blockIdx.x * BM;
  // staging assignments
  int arow = t & (BM - 1);
  int akc  = (t / BM) * (AKV * 4);          // k-chunk start within tile
  int wkr  = t >> 3, wc0 = (t & 7) * 16;    // W: 32 k-rows x 128 cols, 4 f4/thread

  float acc[4 * RQ][8];
  #pragma unroll
  for (int r = 0; r < 4 * RQ; ++r)
    #pragma unroll
    for (int c = 0; c < 8; ++c) acc[r][c] = 0.f;

  for (int kt = 0; kt < 8; ++kt) {
    // loads for THIS tile — short live range across one barrier
    const float* Asrc = (kt < 4) ? agg : x;
    int acol = (kt & 3) * 32 + akc;
    const float* pA = Asrc + (size_t)(i0 + arow) * F + acol;
    float4 va[AKV];
    #pragma unroll
    for (int q = 0; q < AKV; ++q) va[q] = *(const float4*)(pA + q * 4);
    const float* Wsrc = ((kt < 4) ? Wl : Wr) + (size_t)((kt & 3) * 32 + wkr) * F + wc0;
    float4 vw[4];
    #pragma unroll
    for (int q = 0; q < 4; ++q) vw[q] = *(const float4*)(Wsrc + q * 4);
    __syncthreads();                      // previous tile's compute done
    #pragma unroll
    for (int q = 0; q < AKV; ++q) {
      At[akc + q * 4 + 0][arow] = va[q].x;
      At[akc + q * 4 + 1][arow] = va[q].y;
      At[akc + q * 4 + 2][arow] = va[q].z;
      At[akc + q * 4 + 3][arow] = va[q].w;
    }
    #pragma unroll
    for (int q = 0; q < 4; ++q)
      *(float4*)(&Wt[wkr][wc0 + q * 4]) = vw[q];
    __syncthreads();                      // tile ready
    #pragma unroll
    for (int k = 0; k < 32; ++k) {
      float4 a0 = *(float4*)(&At[k][ty * 4]);
      float4 w0 = *(float4*)(&Wt[k][tx * 4]);
      float4 w1 = *(float4*)(&Wt[k][64 + tx * 4]);
      float wr[8] = {w0.x, w0.y, w0.z, w0.w, w1.x, w1.y, w1.z, w1.w};
      float ar0[4] = {a0.x, a0.y, a0.z, a0.w};
      #pragma unroll
      for (int r = 0; r < 4; ++r)
        #pragma unroll
        for (int c = 0; c < 8; ++c)
          acc[r][c] += ar0[r] * wr[c];
      if (RQ == 2) {
        float4 a1 = *(float4*)(&At[k][64 + ty * 4]);
        float ar1[4] = {a1.x, a1.y, a1.z, a1.w};
        #pragma unroll
        for (int r = 0; r < 4; ++r)
          #pragma unroll
          for (int c = 0; c < 8; ++c)
            acc[4 + r][c] += ar1[r] * wr[c];
      }
    }
  }

  float4 bb0 = *(const float4*)(bias + tx * 4);
  float4 bb1 = *(const float4*)(bias + 64 + tx * 4);
  float4 pw0 = *(const float4*)(pw + tx * 4);
  float4 pw1 = *(const float4*)(pw + 64 + tx * 4);
  float inorm = *invn;
  #pragma unroll
  for (int r = 0; r < 4 * RQ; ++r) {
    int row = i0 + ((r < 4) ? (ty * 4 + r) : (64 + ty * 4 + r - 4));
    float4 o0, o1;
    o0.x = fmaxf(acc[r][0] + bb0.x, 0.f);
    o0.y = fmaxf(acc[r][1] + bb0.y, 0.f);
    o0.z = fmaxf(acc[r][2] + bb0.z, 0.f);
    o0.w = fmaxf(acc[r][3] + bb0.w, 0.f);
    o1.x = fmaxf(acc[r][4] + bb1.x, 0.f);
    o1.y = fmaxf(acc[r][5] + bb1.y, 0.f);
    o1.z = fmaxf(acc[r][6] + bb1.z, 0.f);
    o1.w = fmaxf(acc[r][7] + bb1.w, 0.f);
    *(float4*)(h + (size_t)row * F + tx * 4) = o0;
    *(float4*)(h + (size_t)row * F + 64 + tx * 4) = o1;
    float p = o0.x * pw0.x + o0.y * pw0.y + o0.z * pw0.z + o0.w * pw0.w
            + o1.x * pw1.x + o1.y * pw1.y + o1.z * pw1.z + o1.w * pw1.w;
    #pragma unroll
    for (int off = 8; off; off >>= 1) p += __shfl_xor(p, off);  // across 16 tx lanes
    if (tx == 0) score[row] = tanhf(p * inorm);
  }
}

// ------------------------------------------------------------------
// Per-graph k-th-largest via 4-pass radix select on sortable float
// bits (exact threshold + tie quota).
// ------------------------------------------------------------------
__global__ __launch_bounds__(256) void topk_kernel(
    const float* __restrict__ score, float* __restrict__ thr,
    int* __restrict__ quota, int* __restrict__ tiecur,
    int* __restrict__ curg, int nper, int k) {
  __shared__ unsigned su[2048];
  __shared__ int hist[256];
  __shared__ int vsel;
  int b = blockIdx.x, t = threadIdx.x;
  for (int i = t; i < nper; i += 256) {
    unsigned u = __float_as_uint(score[b * nper + i]);
    su[i] = (u & 0x80000000u) ? ~u : (u | 0x80000000u);   // order-preserving
  }
  __syncthreads();
  unsigned prefix = 0;
  int rem = k;                     // rank among prefix-matching values
  for (int shift = 24; shift >= 0; shift -= 8) {
    hist[t] = 0;
    __syncthreads();
    unsigned maskhi = (shift == 24) ? 0u : (0xFFFFFFFFu << (shift + 8));
    for (int i = t; i < nper; i += 256) {
      unsigned u = su[i];
      if ((u & maskhi) == prefix) atomicAdd(&hist[(u >> shift) & 255], 1);
    }
    __syncthreads();
    // suffix sums: hist[t] = count(byte >= t)
    for (int off = 1; off < 256; off <<= 1) {
      int v = (t + off < 256) ? hist[t + off] : 0;
      __syncthreads();
      hist[t] += v;
      __syncthreads();
    }
    if (hist[t] >= rem && (t == 255 || hist[t + 1] < rem)) vsel = t;
    __syncthreads();
    int v = vsel;
    int above = (v == 255) ? 0 : hist[v + 1];   // count strictly greater (this byte)
    rem -= above;
    prefix |= ((unsigned)v << shift);
    __syncthreads();
  }
  if (t == 0) {
    unsigned s = prefix;
    unsigned ub = (s >> 31) ? (s & 0x7FFFFFFFu) : ~s;     // inverse map
    thr[b] = __uint_as_float(ub);
    quota[b] = rem;                 // ties to keep = k - count(>T)
    tiecur[b * CPAD] = 0; curg[b * CPAD] = 0;
  }
}

// ------------------------------------------------------------------
// Select + gate + compact + FUSED readout partials.
// ------------------------------------------------------------------
__global__ __launch_bounds__(256) void select_kernel(
    const float* __restrict__ h, const float* __restrict__ score,
    const float* __restrict__ thr, const int* __restrict__ quota,
    int* __restrict__ tiecur, int* __restrict__ curg,
    const int* __restrict__ origA, int* __restrict__ origB,
    int* __restrict__ m, float* __restrict__ xnext,
    const int* __restrict__ rowstart, const int* __restrict__ deg,
    int2* __restrict__ sd2, float* __restrict__ pmax, float* __restrict__ psum,
    int nper, int k) {
  __shared__ int   snid[64];
  __shared__ float ssc[64];
  __shared__ float smax[8][128], ssum[8][128];
  int t = threadIdx.x;
  int base = blockIdx.x * 64;        // 64 consecutive nodes, same graph
  int b = base / nper;               // nper multiple of 64
  if (t < 64) {                      // wave 0 exactly
    int i = base + t;
    float sc = score[i];
    float T = thr[b];
    int keep = (sc > T) ? 1 : 0;
    if (!keep && sc == T) keep = (atomicAdd(&tiecur[b * CPAD], 1) < quota[b]) ? 1 : 0;
    unsigned long long mask = __ballot(keep);
    int pre = __popcll(mask & ((1ull << t) - 1ull));
    int tot = __popcll(mask);
    int wbase = 0;
    if (t == 0 && tot) wbase = atomicAdd(&curg[b * CPAD], tot);
    wbase = __shfl(wbase, 0);
    int nid = keep ? (b * k + wbase + pre) : -1;
    int orig = origA[i];
    m[orig] = nid;
    if (nid >= 0) {
      origB[nid] = orig;
      sd2[nid] = make_int2(rowstart[orig], deg[orig]);
    }
    snid[t] = nid; ssc[t] = sc;
  }
  __syncthreads();
  int g = t >> 5, l32 = t & 31;
  float4 pm = make_float4(-INFINITY, -INFINITY, -INFINITY, -INFINITY);
  float4 ps = make_float4(0.f, 0.f, 0.f, 0.f);
  for (int n = g; n < 64; n += 8) {
    int nid = snid[n];
    if (nid >= 0) {
      float sc = ssc[n];
      float4 v = *(const float4*)(h + (size_t)(base + n) * F + l32 * 4);
      v.x *= sc; v.y *= sc; v.z *= sc; v.w *= sc;
      *(float4*)(xnext + (size_t)nid * F + l32 * 4) = v;
      pm.x = fmaxf(pm.x, v.x); pm.y = fmaxf(pm.y, v.y);
      pm.z = fmaxf(pm.z, v.z); pm.w = fmaxf(pm.w, v.w);
      ps.x += v.x; ps.y += v.y; ps.z += v.z; ps.w += v.w;
    }
  }
  *(float4*)(&smax[g][l32 * 4]) = pm;
  *(float4*)(&ssum[g][l32 * 4]) = ps;
  __syncthreads();
  if (t < 128) {
    float mx = -INFINITY, sm = 0.f;
    #pragma unroll
    for (int gg = 0; gg < 8; ++gg) {
      mx = fmaxf(mx, smax[gg][t]);
      sm += ssum[gg][t];
    }
    int nblk = nper >> 6;                       // select-blocks per graph
    int blkpos = blockIdx.x - b * nblk;
    int o = (b * MAXBLK + blkpos) * 128 + t;
    pmax[o] = mx; psum[o] = sm;
  }
}

// Readout: combine the per-select-block partials, z[b] += [max | mean]
__global__ void readout_final(const float* __restrict__ pmax,
                              const float* __restrict__ psum,
                              float* __restrict__ z, int k, int nblk) {
  int b = blockIdx.x, f = threadIdx.x;   // 128 threads
  float mx = -INFINITY, sm = 0.f;
  for (int ch = 0; ch < nblk; ++ch) {
    int o = (b * MAXBLK + ch) * 128 + f;
    mx = fmaxf(mx, pmax[o]);
    sm += psum[o];
  }
  z[b * 256 + f]       += mx;
  z[b * 256 + 128 + f] += sm / (float)k;
}

// ------------------------------------------------------------------
// MLP head: 256 -> 128 relu -> 64 relu -> 2 -> log_softmax
// ------------------------------------------------------------------
__global__ void mlp_kernel(const float* __restrict__ z,
                           const float* __restrict__ l1w, const float* __restrict__ l1b,
                           const float* __restrict__ l2w, const float* __restrict__ l2b,
                           const float* __restrict__ l3w, const float* __restrict__ l3b,
                           float* __restrict__ out) {
  int b = blockIdx.x, t = threadIdx.x;    // 128 threads
  __shared__ float zz[256], o1[128], o2[64], lg[2];
  zz[t]       = z[b * 256 + t];
  zz[t + 128] = z[b * 256 + 128 + t];
  __syncthreads();
  float a = l1b[t];
  for (int i = 0; i < 256; ++i) a += zz[i] * l1w[i * 128 + t];
  o1[t] = fmaxf(a, 0.f);
  __syncthreads();
  if (t < 64) {
    float a2 = l2b[t];
    for (int i = 0; i < 128; ++i) a2 += o1[i] * l2w[i * 64 + t];
    o2[t] = fmaxf(a2, 0.f);
  }
  __syncthreads();
  if (t < 2) {
    float a3 = l3b[t];
    for (int i = 0; i < 64; ++i) a3 += o2[i] * l3w[i * 2 + t];
    lg[t] = a3;
  }
  __syncthreads();
  if (t == 0) {
    float mmax = fmaxf(lg[0], lg[1]);
    float lse = mmax + logf(expf(lg[0] - mmax) + expf(lg[1] - mmax));
    out[b * 2 + 0] = lg[0] - lse;
    out[b * 2 + 1] = lg[1] - lse;
  }
}

// ------------------------------------------------------------------
extern "C" void kernel_launch(void* const* d_in, const int* in_sizes, int n_in,
                              void* d_out, int out_size, void* d_ws, size_t ws_size,
                              hipStream_t stream) {
  const float* x   = (const float*)d_in[0];
  const int*   src = (const int*)d_in[1];
  const int*   dst = (const int*)d_in[2];
  const float* Wl[3] = {(const float*)d_in[3], (const float*)d_in[7],  (const float*)d_in[11]};
  const float* bs[3] = {(const float*)d_in[4], (const float*)d_in[8],  (const float*)d_in[12]};
  const float* Wr[3] = {(const float*)d_in[5], (const float*)d_in[9],  (const float*)d_in[13]};
  const float* pw[3] = {(const float*)d_in[6], (const float*)d_in[10], (const float*)d_in[14]};
  const float* l1w = (const float*)d_in[15]; const float* l1b = (const float*)d_in[16];
  const float* l2w = (const float*)d_in[17]; const float* l2b = (const float*)d_in[18];
  const float* l3w = (const float*)d_in[19]; const float* l3b = (const float*)d_in[20];
  float* out = (float*)d_out;

  // workspace carve (~115 MB)
  char* p = (char*)d_ws;
  auto take = [&](size_t bytes) { char* q = p; p += (bytes + 255) & ~(size_t)255; return q; };
  float* aggh   = (float*)take((size_t)NT1 * F * 4);     // agg(mean), then h (aliased)
  float* xbuf   = (float*)take((size_t)65536 * F * 4);   // pooled features
  float* score  = (float*)take((size_t)NT1 * 4);
  int* deg      = (int*)take((size_t)NT1 * 4);
  int* rowstart = (int*)take((size_t)NT1 * 4);
  int* cursor   = (int*)take((size_t)NT1 * 4);
  int* m        = (int*)take((size_t)NT1 * 4);
  int* origA    = (int*)take((size_t)NT1 * 4);
  int* origB    = (int*)take((size_t)NT1 * 4);
  int2* sd2     = (int2*)take((size_t)NT1 * 8);
  int* csr      = (int*)take((size_t)ETOT * 4);
  int* bsum     = (int*)take(128 * 4);
  float* thr    = (float*)take(NB * 4);
  int* quota    = (int*)take(NB * 4);
  int* tiecur   = (int*)take(NB * CPAD * 4);   // line-padded counters
  int* curg     = (int*)take(NB * CPAD * 4);
  float* z      = (float*)take(NB * 256 * 4);
  float* pmax   = (float*)take((size_t)NB * MAXBLK * F * 4);
  float* psum   = (float*)take((size_t)NB * MAXBLK * F * 4);
  float* invn   = (float*)take(4);

  hipMemsetAsync(deg, 0, (size_t)NT1 * 4, stream);
  hipMemsetAsync(z, 0, (size_t)NB * 256 * 4, stream);

  // CSR on original ids (graph topology is fixed for the whole forward)
  hist_kernel<<<ETOT / 256, 256, 0, stream>>>(dst, deg);
  scan1_kernel<<<128, 256, 0, stream>>>(deg, rowstart, bsum);
  scan2_kernel<<<1, 128, 0, stream>>>(bsum);
  scan3_kernel<<<128, 256, 0, stream>>>(rowstart, bsum, cursor);
  fill_kernel<<<ETOT / 256, 256, 0, stream>>>(src, dst, cursor, csr);
  init_id_kernel<<<NT1 / 256, 256, 0, stream>>>(m, origA, rowstart, deg, sd2);

  int NT = NT1, nper = 2048;
  const float* xin = x;
  int* oin = origA; int* oout = origB;
  for (int s = 0; s < 3; ++s) {
    int k = nper / 2;
    if (s == 0)
      agg_kernel<0><<<NT / 8, 256, 0, stream>>>(xin, csr, m, sd2, aggh, pw[s], invn);
    else
      agg_kernel<1><<<NT / 8, 256, 0, stream>>>(xin, csr, m, sd2, aggh, pw[s], invn);
    if (s == 0)
      sage_gemm<128><<<NT / 128, 256, 0, stream>>>(aggh, xin, Wl[s], Wr[s], bs[s], aggh,
                                                   pw[s], invn, score);
    else
      sage_gemm<64><<<NT / 64, 256, 0, stream>>>(aggh, xin, Wl[s], Wr[s], bs[s], aggh,
                                                 pw[s], invn, score);
    topk_kernel<<<NB, 256, 0, stream>>>(score, thr, quota, tiecur, curg, nper, k);
    select_kernel<<<NT / 64, 256, 0, stream>>>(aggh, score, thr, quota, tiecur, curg,
                                               oin, oout, m, xbuf, rowstart, deg, sd2,
                                               pmax, psum, nper, k);
    readout_final<<<NB, 128, 0, stream>>>(pmax, psum, z, k, nper >> 6);
    NT = NB * k; nper = k; xin = xbuf;
    int* tmp = oin; oin = oout; oout = tmp;
  }
  mlp_kernel<<<NB, 128, 0, stream>>>(z, l1w, l1b, l2w, l2b, l3w, l3b, out);
}

// Round 11
// 648.135 us; speedup vs baseline: 1.1184x; 1.1184x over previous
//
#include <hip/hip_runtime.h>
#include <cmath>

#define NT1  131072     // B*N total nodes at stage 1
#define ETOT 2097152    // total edges (B*N*DEG)
#define NB   64         // graphs
#define F    128        // feature dim
#define CPAD 32         // per-graph atomic counter stride (ints) = 128B line
#define MAXBLK 32       // max select-blocks per graph (stage 1: 2048/64)

// ------------------------------------------------------------------
// CSR build (on ORIGINAL node ids; reused by all 3 stages via m[])
// ------------------------------------------------------------------
__global__ void hist_kernel(const int* __restrict__ dst, int* __restrict__ deg) {
  int e = blockIdx.x * blockDim.x + threadIdx.x;
  if (e < ETOT) atomicAdd(&deg[dst[e]], 1);
}

__global__ void scan1_kernel(const int* __restrict__ deg, int* __restrict__ rowstart,
                             int* __restrict__ bsum) {
  __shared__ int ls[256];
  int base = blockIdx.x * 1024;
  int t = threadIdx.x;
  int i = base + t * 4;
  int a0 = deg[i], a1 = deg[i + 1], a2 = deg[i + 2], a3 = deg[i + 3];
  int s = a0 + a1 + a2 + a3;
  ls[t] = s;
  __syncthreads();
  for (int off = 1; off < 256; off <<= 1) {
    int v = (t >= off) ? ls[t - off] : 0;
    __syncthreads();
    ls[t] += v;
    __syncthreads();
  }
  int excl = ls[t] - s;
  rowstart[i]     = excl;
  rowstart[i + 1] = excl + a0;
  rowstart[i + 2] = excl + a0 + a1;
  rowstart[i + 3] = excl + a0 + a1 + a2;
  if (t == 255) bsum[blockIdx.x] = ls[255];
}

__global__ void scan2_kernel(int* __restrict__ bsum) {
  __shared__ int ls[128];
  int t = threadIdx.x;
  int v0 = bsum[t];
  ls[t] = v0;
  __syncthreads();
  for (int off = 1; off < 128; off <<= 1) {
    int v = (t >= off) ? ls[t - off] : 0;
    __syncthreads();
    ls[t] += v;
    __syncthreads();
  }
  bsum[t] = ls[t] - v0;   // exclusive
}

// adds block offsets; also writes cursor = rowstart (fill's atomic cursor)
__global__ void scan3_kernel(int* __restrict__ rowstart, const int* __restrict__ bsum,
                             int* __restrict__ cursor) {
  int base = blockIdx.x * 1024;
  int off = bsum[blockIdx.x];
  int i = base + threadIdx.x * 4;
  int r0 = rowstart[i] + off, r1 = rowstart[i + 1] + off;
  int r2 = rowstart[i + 2] + off, r3 = rowstart[i + 3] + off;
  rowstart[i] = r0; rowstart[i + 1] = r1; rowstart[i + 2] = r2; rowstart[i + 3] = r3;
  cursor[i] = r0; cursor[i + 1] = r1; cursor[i + 2] = r2; cursor[i + 3] = r3;
}

__global__ void fill_kernel(const int* __restrict__ src, const int* __restrict__ dst,
                            int* __restrict__ cursor, int* __restrict__ csr) {
  int e = blockIdx.x * blockDim.x + threadIdx.x;
  if (e < ETOT) {
    int pos = atomicAdd(&cursor[dst[e]], 1);
    csr[pos] = src[e];
  }
}

// identity alive-map, orig list, and stage-1 (rowstart,deg) pairs
__global__ void init_id_kernel(int* __restrict__ m, int* __restrict__ orig,
                               const int* __restrict__ rowstart,
                               const int* __restrict__ deg, int2* __restrict__ sd2) {
  int v = blockIdx.x * blockDim.x + threadIdx.x;
  m[v] = v; orig[v] = v;
  sd2[v] = make_int2(rowstart[v], deg[v]);
}

// ------------------------------------------------------------------
// Neighbor MEAN aggregation: 32-lane group per node, lane = float4
// slice, shfl-broadcast ids, 8-deep-unrolled predicated gather.
// MAP=1 folds the alive-map lookup into the id fetch (stages 2/3).
// Block 0 computes invn = 1/||pw||.
// ------------------------------------------------------------------
template <int MAP>
__global__ __launch_bounds__(256) void agg_kernel(
    const float* __restrict__ xin, const int* __restrict__ ids,
    const int* __restrict__ m, const int2* __restrict__ sd2,
    float* __restrict__ agg, const float* __restrict__ pw,
    float* __restrict__ invn) {
  if (blockIdx.x == 0 && threadIdx.x < 64) {
    int l = threadIdx.x;
    float vv = pw[l] * pw[l] + pw[l + 64] * pw[l + 64];
    #pragma unroll
    for (int o = 32; o; o >>= 1) vv += __shfl_xor(vv, o);
    if (l == 0) *invn = 1.0f / sqrtf(vv);
  }
  int swz = gridDim.x >> 3;                    // blocks per XCD slice
  int nb  = (blockIdx.x & 7) * swz + (blockIdx.x >> 3);
  int g = threadIdx.x >> 5, l = threadIdx.x & 31;
  int jd = nb * 8 + g;
  int2 sdv = sd2[jd];
  int s = sdv.x, d = sdv.y;
  float4 acc = make_float4(0.f, 0.f, 0.f, 0.f);
  int c = 0;
  for (int base = 0; base < d; base += 32) {
    int dc = min(32, d - base);
    int nbid = -1;
    if (l < dc) {
      int e = __builtin_nontemporal_load(&ids[s + base + l]);
      nbid = MAP ? m[e] : e;
    }
    int j = 0;
    for (; j + 8 <= dc; j += 8) {
      int n[8];
      float4 v[8];
      #pragma unroll
      for (int q = 0; q < 8; ++q) n[q] = __shfl(nbid, j + q, 32);
      #pragma unroll
      for (int q = 0; q < 8; ++q)
        v[q] = *(const float4*)(xin + (size_t)max(n[q], 0) * F + l * 4);
      #pragma unroll
      for (int q = 0; q < 8; ++q)
        if (n[q] >= 0) { acc.x += v[q].x; acc.y += v[q].y; acc.z += v[q].z; acc.w += v[q].w; ++c; }
    }
    for (; j + 4 <= dc; j += 4) {
      int n0 = __shfl(nbid, j, 32);
      int n1 = __shfl(nbid, j + 1, 32);
      int n2 = __shfl(nbid, j + 2, 32);
      int n3 = __shfl(nbid, j + 3, 32);
      float4 v0 = *(const float4*)(xin + (size_t)max(n0, 0) * F + l * 4);
      float4 v1 = *(const float4*)(xin + (size_t)max(n1, 0) * F + l * 4);
      float4 v2 = *(const float4*)(xin + (size_t)max(n2, 0) * F + l * 4);
      float4 v3 = *(const float4*)(xin + (size_t)max(n3, 0) * F + l * 4);
      if (n0 >= 0) { acc.x += v0.x; acc.y += v0.y; acc.z += v0.z; acc.w += v0.w; ++c; }
      if (n1 >= 0) { acc.x += v1.x; acc.y += v1.y; acc.z += v1.z; acc.w += v1.w; ++c; }
      if (n2 >= 0) { acc.x += v2.x; acc.y += v2.y; acc.z += v2.z; acc.w += v2.w; ++c; }
      if (n3 >= 0) { acc.x += v3.x; acc.y += v3.y; acc.z += v3.z; acc.w += v3.w; ++c; }
    }
    for (; j < dc; ++j) {
      int n0 = __shfl(nbid, j, 32);
      if (n0 >= 0) {
        float4 v0 = *(const float4*)(xin + (size_t)n0 * F + l * 4);
        acc.x += v0.x; acc.y += v0.y; acc.z += v0.z; acc.w += v0.w; ++c;
      }
    }
  }
  float inv = 1.0f / (float)max(c, 1);
  acc.x *= inv; acc.y *= inv; acc.z *= inv; acc.w *= inv;
  *(float4*)(agg + (size_t)jd * F + l * 4) = acc;
}

// ------------------------------------------------------------------
// Fused SAGE linear + pool scoring, BM x 128 tile / 256 threads.
// R5 load shape (loop-top, short live range — the measured winner) +
// DOUBLE-buffered LDS with ONE barrier per tile (16 total, vs 32):
//   iter kt: load regs(kt) -> write LDS[kt&1] -> bar -> compute
// write(kt) to buf is safe: it follows this wave's barrier(kt-1),
// which globally orders it after all waves' compute(kt-2) on buf.
//   h = relu( mean @ Wl + x @ Wr + b );  score = tanh((h.pw)*invn)
// h aliases agg — safe: block touches only its own BM rows.
// ------------------------------------------------------------------
template <int BM>
__global__ __launch_bounds__(256) void sage_gemm(
    const float* agg, const float* __restrict__ x,
    const float* __restrict__ Wl, const float* __restrict__ Wr,
    const float* __restrict__ bias, float* h,
    const float* __restrict__ pw, const float* __restrict__ invn,
    float* __restrict__ score) {
  constexpr int RQ = BM / 64;               // row quadrants (2 or 1)
  __shared__ float At[2][16][BM + 4];
  __shared__ float Wt[2][16][132];
  int t  = threadIdx.x;
  int tx = t & 15, ty = t >> 4;             // 16x16 thread grid
  int i0 = blockIdx.x * BM;
  // staging assignments
  int arow, akc;
  if (BM == 128) { arow = t & 127; akc = (t >> 7) * 8; }   // 2 chunks x 8k
  else           { arow = t & 63;  akc = (t >> 6) * 4; }   // 4 chunks x 4k
  int wkr = t >> 4, wc0 = (t & 15) * 8;     // W: 16 k-rows x 128 cols

  float acc[4 * RQ][8];
  #pragma unroll
  for (int r = 0; r < 4 * RQ; ++r)
    #pragma unroll
    for (int c = 0; c < 8; ++c) acc[r][c] = 0.f;

  for (int kt = 0; kt < 16; ++kt) {
    int buf = kt & 1;
    // loads for THIS tile — short live range, written right below
    const float* Asrc = (kt < 8) ? agg : x;
    int acol = (kt & 7) * 16 + akc;
    const float* pA = Asrc + (size_t)(i0 + arow) * F + acol;
    float4 va0 = *(const float4*)pA;
    float4 va1;
    if (BM == 128) va1 = *(const float4*)(pA + 4);
    const float* Wsrc = ((kt < 8) ? Wl : Wr) + (size_t)((kt & 7) * 16 + wkr) * F + wc0;
    float4 vw0 = *(const float4*)Wsrc;
    float4 vw1 = *(const float4*)(Wsrc + 4);
    At[buf][akc + 0][arow] = va0.x; At[buf][akc + 1][arow] = va0.y;
    At[buf][akc + 2][arow] = va0.z; At[buf][akc + 3][arow] = va0.w;
    if (BM == 128) {
      At[buf][akc + 4][arow] = va1.x; At[buf][akc + 5][arow] = va1.y;
      At[buf][akc + 6][arow] = va1.z; At[buf][akc + 7][arow] = va1.w;
    }
    *(float4*)(&Wt[buf][wkr][wc0]) = vw0;
    *(float4*)(&Wt[buf][wkr][wc0 + 4]) = vw1;
    __syncthreads();                      // tile ready (single barrier/tile)
    #pragma unroll
    for (int k = 0; k < 16; ++k) {
      float4 a0 = *(float4*)(&At[buf][k][ty * 4]);
      float4 w0 = *(float4*)(&Wt[buf][k][tx * 4]);
      float4 w1 = *(float4*)(&Wt[buf][k][64 + tx * 4]);
      float wr[8] = {w0.x, w0.y, w0.z, w0.w, w1.x, w1.y, w1.z, w1.w};
      float ar0[4] = {a0.x, a0.y, a0.z, a0.w};
      #pragma unroll
      for (int r = 0; r < 4; ++r)
        #pragma unroll
        for (int c = 0; c < 8; ++c)
          acc[r][c] += ar0[r] * wr[c];
      if (RQ == 2) {
        float4 a1 = *(float4*)(&At[buf][k][64 + ty * 4]);
        float ar1[4] = {a1.x, a1.y, a1.z, a1.w};
        #pragma unroll
        for (int r = 0; r < 4; ++r)
          #pragma unroll
          for (int c = 0; c < 8; ++c)
            acc[4 + r][c] += ar1[r] * wr[c];
      }
    }
  }

  float4 bb0 = *(const float4*)(bias + tx * 4);
  float4 bb1 = *(const float4*)(bias + 64 + tx * 4);
  float4 pw0 = *(const float4*)(pw + tx * 4);
  float4 pw1 = *(const float4*)(pw + 64 + tx * 4);
  float inorm = *invn;
  #pragma unroll
  for (int r = 0; r < 4 * RQ; ++r) {
    int row = i0 + ((r < 4) ? (ty * 4 + r) : (64 + ty * 4 + r - 4));
    float4 o0, o1;
    o0.x = fmaxf(acc[r][0] + bb0.x, 0.f);
    o0.y = fmaxf(acc[r][1] + bb0.y, 0.f);
    o0.z = fmaxf(acc[r][2] + bb0.z, 0.f);
    o0.w = fmaxf(acc[r][3] + bb0.w, 0.f);
    o1.x = fmaxf(acc[r][4] + bb1.x, 0.f);
    o1.y = fmaxf(acc[r][5] + bb1.y, 0.f);
    o1.z = fmaxf(acc[r][6] + bb1.z, 0.f);
    o1.w = fmaxf(acc[r][7] + bb1.w, 0.f);
    *(float4*)(h + (size_t)row * F + tx * 4) = o0;
    *(float4*)(h + (size_t)row * F + 64 + tx * 4) = o1;
    float p = o0.x * pw0.x + o0.y * pw0.y + o0.z * pw0.z + o0.w * pw0.w
            + o1.x * pw1.x + o1.y * pw1.y + o1.z * pw1.z + o1.w * pw1.w;
    #pragma unroll
    for (int off = 8; off; off >>= 1) p += __shfl_xor(p, off);  // across 16 tx lanes
    if (tx == 0) score[row] = tanhf(p * inorm);
  }
}

// ------------------------------------------------------------------
// Per-graph k-th-largest via 4-pass radix select on sortable float
// bits (exact threshold + tie quota).
// ------------------------------------------------------------------
__global__ __launch_bounds__(256) void topk_kernel(
    const float* __restrict__ score, float* __restrict__ thr,
    int* __restrict__ quota, int* __restrict__ tiecur,
    int* __restrict__ curg, int nper, int k) {
  __shared__ unsigned su[2048];
  __shared__ int hist[256];
  __shared__ int vsel;
  int b = blockIdx.x, t = threadIdx.x;
  for (int i = t; i < nper; i += 256) {
    unsigned u = __float_as_uint(score[b * nper + i]);
    su[i] = (u & 0x80000000u) ? ~u : (u | 0x80000000u);   // order-preserving
  }
  __syncthreads();
  unsigned prefix = 0;
  int rem = k;                     // rank among prefix-matching values
  for (int shift = 24; shift >= 0; shift -= 8) {
    hist[t] = 0;
    __syncthreads();
    unsigned maskhi = (shift == 24) ? 0u : (0xFFFFFFFFu << (shift + 8));
    for (int i = t; i < nper; i += 256) {
      unsigned u = su[i];
      if ((u & maskhi) == prefix) atomicAdd(&hist[(u >> shift) & 255], 1);
    }
    __syncthreads();
    // suffix sums: hist[t] = count(byte >= t)
    for (int off = 1; off < 256; off <<= 1) {
      int v = (t + off < 256) ? hist[t + off] : 0;
      __syncthreads();
      hist[t] += v;
      __syncthreads();
    }
    if (hist[t] >= rem && (t == 255 || hist[t + 1] < rem)) vsel = t;
    __syncthreads();
    int v = vsel;
    int above = (v == 255) ? 0 : hist[v + 1];   // count strictly greater (this byte)
    rem -= above;
    prefix |= ((unsigned)v << shift);
    __syncthreads();
  }
  if (t == 0) {
    unsigned s = prefix;
    unsigned ub = (s >> 31) ? (s & 0x7FFFFFFFu) : ~s;     // inverse map
    thr[b] = __uint_as_float(ub);
    quota[b] = rem;                 // ties to keep = k - count(>T)
    tiecur[b * CPAD] = 0; curg[b * CPAD] = 0;
  }
}

// ------------------------------------------------------------------
// Select + gate + compact + FUSED readout partials (per-stage region
// of pmax/psum is selected by the caller via pointer offset).
// ------------------------------------------------------------------
__global__ __launch_bounds__(256) void select_kernel(
    const float* __restrict__ h, const float* __restrict__ score,
    const float* __restrict__ thr, const int* __restrict__ quota,
    int* __restrict__ tiecur, int* __restrict__ curg,
    const int* __restrict__ origA, int* __restrict__ origB,
    int* __restrict__ m, float* __restrict__ xnext,
    const int* __restrict__ rowstart, const int* __restrict__ deg,
    int2* __restrict__ sd2, float* __restrict__ pmax, float* __restrict__ psum,
    int nper, int k) {
  __shared__ int   snid[64];
  __shared__ float ssc[64];
  __shared__ float smax[8][128], ssum[8][128];
  int t = threadIdx.x;
  int base = blockIdx.x * 64;        // 64 consecutive nodes, same graph
  int b = base / nper;               // nper multiple of 64
  if (t < 64) {                      // wave 0 exactly
    int i = base + t;
    float sc = score[i];
    float T = thr[b];
    int keep = (sc > T) ? 1 : 0;
    if (!keep && sc == T) keep = (atomicAdd(&tiecur[b * CPAD], 1) < quota[b]) ? 1 : 0;
    unsigned long long mask = __ballot(keep);
    int pre = __popcll(mask & ((1ull << t) - 1ull));
    int tot = __popcll(mask);
    int wbase = 0;
    if (t == 0 && tot) wbase = atomicAdd(&curg[b * CPAD], tot);
    wbase = __shfl(wbase, 0);
    int nid = keep ? (b * k + wbase + pre) : -1;
    int orig = origA[i];
    m[orig] = nid;
    if (nid >= 0) {
      origB[nid] = orig;
      sd2[nid] = make_int2(rowstart[orig], deg[orig]);
    }
    snid[t] = nid; ssc[t] = sc;
  }
  __syncthreads();
  int g = t >> 5, l32 = t & 31;
  float4 pm = make_float4(-INFINITY, -INFINITY, -INFINITY, -INFINITY);
  float4 ps = make_float4(0.f, 0.f, 0.f, 0.f);
  for (int n = g; n < 64; n += 8) {
    int nid = snid[n];
    if (nid >= 0) {
      float sc = ssc[n];
      float4 v = *(const float4*)(h + (size_t)(base + n) * F + l32 * 4);
      v.x *= sc; v.y *= sc; v.z *= sc; v.w *= sc;
      *(float4*)(xnext + (size_t)nid * F + l32 * 4) = v;
      pm.x = fmaxf(pm.x, v.x); pm.y = fmaxf(pm.y, v.y);
      pm.z = fmaxf(pm.z, v.z); pm.w = fmaxf(pm.w, v.w);
      ps.x += v.x; ps.y += v.y; ps.z += v.z; ps.w += v.w;
    }
  }
  *(float4*)(&smax[g][l32 * 4]) = pm;
  *(float4*)(&ssum[g][l32 * 4]) = ps;
  __syncthreads();
  if (t < 128) {
    float mx = -INFINITY, sm = 0.f;
    #pragma unroll
    for (int gg = 0; gg < 8; ++gg) {
      mx = fmaxf(mx, smax[gg][t]);
      sm += ssum[gg][t];
    }
    int nblk = nper >> 6;                       // select-blocks per graph
    int blkpos = blockIdx.x - b * nblk;
    int o = (b * MAXBLK + blkpos) * 128 + t;
    pmax[o] = mx; psum[o] = sm;
  }
}

// ------------------------------------------------------------------
// MLP head with fused 3-stage readout combine:
//   z = sum_s [max_s | mean_s];  256 -> 128 relu -> 64 relu -> 2 -> lsm
// ------------------------------------------------------------------
__global__ void mlp_kernel(const float* __restrict__ pmax,
                           const float* __restrict__ psum,
                           const float* __restrict__ l1w, const float* __restrict__ l1b,
                           const float* __restrict__ l2w, const float* __restrict__ l2b,
                           const float* __restrict__ l3w, const float* __restrict__ l3b,
                           float* __restrict__ out) {
  int b = blockIdx.x, t = threadIdx.x;    // 128 threads
  __shared__ float zz[256], o1[128], o2[64], lg[2];
  const int nblk3[3] = {32, 16, 8};
  const float invk3[3] = {1.0f / 1024.f, 1.0f / 512.f, 1.0f / 256.f};
  float summax = 0.f, summean = 0.f;
  #pragma unroll
  for (int s = 0; s < 3; ++s) {
    const float* pm = pmax + (size_t)s * NB * MAXBLK * F;
    const float* ps = psum + (size_t)s * NB * MAXBLK * F;
    float mx = -INFINITY, sm = 0.f;
    for (int ch = 0; ch < nblk3[s]; ++ch) {
      int o = (b * MAXBLK + ch) * 128 + t;
      mx = fmaxf(mx, pm[o]);
      sm += ps[o];
    }
    summax += mx;
    summean += sm * invk3[s];
  }
  zz[t] = summax;
  zz[t + 128] = summean;
  __syncthreads();
  float a = l1b[t];
  for (int i = 0; i < 256; ++i) a += zz[i] * l1w[i * 128 + t];
  o1[t] = fmaxf(a, 0.f);
  __syncthreads();
  if (t < 64) {
    float a2 = l2b[t];
    for (int i = 0; i < 128; ++i) a2 += o1[i] * l2w[i * 64 + t];
    o2[t] = fmaxf(a2, 0.f);
  }
  __syncthreads();
  if (t < 2) {
    float a3 = l3b[t];
    for (int i = 0; i < 64; ++i) a3 += o2[i] * l3w[i * 2 + t];
    lg[t] = a3;
  }
  __syncthreads();
  if (t == 0) {
    float mmax = fmaxf(lg[0], lg[1]);
    float lse = mmax + logf(expf(lg[0] - mmax) + expf(lg[1] - mmax));
    out[b * 2 + 0] = lg[0] - lse;
    out[b * 2 + 1] = lg[1] - lse;
  }
}

// ------------------------------------------------------------------
extern "C" void kernel_launch(void* const* d_in, const int* in_sizes, int n_in,
                              void* d_out, int out_size, void* d_ws, size_t ws_size,
                              hipStream_t stream) {
  const float* x   = (const float*)d_in[0];
  const int*   src = (const int*)d_in[1];
  const int*   dst = (const int*)d_in[2];
  const float* Wl[3] = {(const float*)d_in[3], (const float*)d_in[7],  (const float*)d_in[11]};
  const float* bs[3] = {(const float*)d_in[4], (const float*)d_in[8],  (const float*)d_in[12]};
  const float* Wr[3] = {(const float*)d_in[5], (const float*)d_in[9],  (const float*)d_in[13]};
  const float* pw[3] = {(const float*)d_in[6], (const float*)d_in[10], (const float*)d_in[14]};
  const float* l1w = (const float*)d_in[15]; const float* l1b = (const float*)d_in[16];
  const float* l2w = (const float*)d_in[17]; const float* l2b = (const float*)d_in[18];
  const float* l3w = (const float*)d_in[19]; const float* l3b = (const float*)d_in[20];
  float* out = (float*)d_out;

  // workspace carve (~120 MB)
  char* p = (char*)d_ws;
  auto take = [&](size_t bytes) { char* q = p; p += (bytes + 255) & ~(size_t)255; return q; };
  float* aggh   = (float*)take((size_t)NT1 * F * 4);     // agg(mean), then h (aliased)
  float* xbuf   = (float*)take((size_t)65536 * F * 4);   // pooled features
  float* score  = (float*)take((size_t)NT1 * 4);
  int* deg      = (int*)take((size_t)NT1 * 4);
  int* rowstart = (int*)take((size_t)NT1 * 4);
  int* cursor   = (int*)take((size_t)NT1 * 4);
  int* m        = (int*)take((size_t)NT1 * 4);
  int* origA    = (int*)take((size_t)NT1 * 4);
  int* origB    = (int*)take((size_t)NT1 * 4);
  int2* sd2     = (int2*)take((size_t)NT1 * 8);
  int* csr      = (int*)take((size_t)ETOT * 4);
  int* bsum     = (int*)take(128 * 4);
  float* thr    = (float*)take(NB * 4);
  int* quota    = (int*)take(NB * 4);
  int* tiecur   = (int*)take(NB * CPAD * 4);   // line-padded counters
  int* curg     = (int*)take(NB * CPAD * 4);
  float* pmax   = (float*)take((size_t)3 * NB * MAXBLK * F * 4);  // per-stage regions
  float* psum   = (float*)take((size_t)3 * NB * MAXBLK * F * 4);
  float* invn   = (float*)take(4);

  hipMemsetAsync(deg, 0, (size_t)NT1 * 4, stream);

  // CSR on original ids (graph topology is fixed for the whole forward)
  hist_kernel<<<ETOT / 256, 256, 0, stream>>>(dst, deg);
  scan1_kernel<<<128, 256, 0, stream>>>(deg, rowstart, bsum);
  scan2_kernel<<<1, 128, 0, stream>>>(bsum);
  scan3_kernel<<<128, 256, 0, stream>>>(rowstart, bsum, cursor);
  fill_kernel<<<ETOT / 256, 256, 0, stream>>>(src, dst, cursor, csr);
  init_id_kernel<<<NT1 / 256, 256, 0, stream>>>(m, origA, rowstart, deg, sd2);

  int NT = NT1, nper = 2048;
  const float* xin = x;
  int* oin = origA; int* oout = origB;
  for (int s = 0; s < 3; ++s) {
    int k = nper / 2;
    float* pmaxS = pmax + (size_t)s * NB * MAXBLK * F;
    float* psumS = psum + (size_t)s * NB * MAXBLK * F;
    if (s == 0)
      agg_kernel<0><<<NT / 8, 256, 0, stream>>>(xin, csr, m, sd2, aggh, pw[s], invn);
    else
      agg_kernel<1><<<NT / 8, 256, 0, stream>>>(xin, csr, m, sd2, aggh, pw[s], invn);
    if (s == 0)
      sage_gemm<128><<<NT / 128, 256, 0, stream>>>(aggh, xin, Wl[s], Wr[s], bs[s], aggh,
                                                   pw[s], invn, score);
    else
      sage_gemm<64><<<NT / 64, 256, 0, stream>>>(aggh, xin, Wl[s], Wr[s], bs[s], aggh,
                                                 pw[s], invn, score);
    topk_kernel<<<NB, 256, 0, stream>>>(score, thr, quota, tiecur, curg, nper, k);
    select_kernel<<<NT / 64, 256, 0, stream>>>(aggh, score, thr, quota, tiecur, curg,
                                               oin, oout, m, xbuf, rowstart, deg, sd2,
                                               pmaxS, psumS, nper, k);
    NT = NB * k; nper = k; xin = xbuf;
    int* tmp = oin; oin = oout; oout = tmp;
  }
  mlp_kernel<<<NB, 128, 0, stream>>>(pmax, psum, l1w, l1b, l2w, l2b, l3w, l3b, out);
}